// Round 10
// baseline (1110.176 us; speedup 1.0000x reference)
//
#include <hip/hip_runtime.h>
#include <math.h>

// EthicalGNN: encoder -> 3x(GAT + BN (+ReLU)) -> mean-pool -> 2 MLP heads.
// R10: R7 multi-kernel structure (grid.sync mega-kernel was 4x SLOWER —
// cross-XCD barrier spin, VALUBusy 6.6%). Edge-count merged into layer-0
// GEMM (block-role split); was/wad logit projections computed per-block in
// LDS; heads fused into layer-2 gather via last-block ticket.
// 8 kernels + 1 memset.

#define H4 4
constexpr int TB = 256;

static __device__ __forceinline__ unsigned short f2bf(float f) {
  unsigned u = __float_as_uint(f);
  u += 0x7fffu + ((u >> 16) & 1u);  // round-to-nearest-even
  return (unsigned short)(u >> 16);
}
static __device__ __forceinline__ float bfh(unsigned u) { return __uint_as_float(u << 16); }
static __device__ __forceinline__ float bfl(unsigned u) { return __uint_as_float(u & 0xffff0000u); }

struct Pr {
  const float* x; const int* esrc; const int* edst;
  const float* encW; const float* encb;
  const float* eW1; const float* eb1; const float* eW2; const float* eb2;
  const float* mW1; const float* mb1; const float* mW2; const float* mb2;
  float* hA; float* hB; unsigned short* xpb; float* als; float* ald;
  float* gpart;
  int* col; int* rbeg; int* rend; int* cursor; int* counter; int* ticket;
  float* out; int N; int E;
};

// ==================== GEMM tile (device fn) ====================
// xp(bf16) = hin @ W ; als/ald via in-LDS was/wad = W@a (reassociated).
template <int HC, bool ENC>
__device__ void gemm_tile(const Pr& p, const float* __restrict__ hin,
                          const float* __restrict__ W,
                          const float* __restrict__ a_s, const float* __restrict__ a_d,
                          float* hs, float* lws, float* lwd, int n0) {
  constexpr int C = HC / H4;
  int tid = threadIdx.x;
  // stage h tile into LDS
  if (ENC) {
    for (int idx = tid; idx < 1024; idx += HC) {
      int i = idx >> 6, j = idx & 63;
      int n = n0 + i;
      float a = 0.f;
      if (n < p.N) {
        a = p.encb[j];
#pragma unroll
        for (int k = 0; k < 5; ++k) a += p.x[n * 5 + k] * p.encW[k * 64 + j];
      }
      hs[idx] = a;
    }
  } else {
    for (int idx = tid; idx < 1024; idx += HC) {
      int n = n0 + (idx >> 6);
      hs[idx] = (n < p.N) ? hin[(size_t)n0 * 64 + idx] : 0.f;
    }
  }
  // was/wad[k,h] = sum_c W[k, h*C+c] * a[h,c]  (per-block, into LDS)
  for (int i = tid; i < 256; i += HC) {
    int k = i >> 2, h = i & 3;
    const float* wr = W + k * HC + h * C;
    const float* ar = a_s + h * C;
    const float* dr = a_d + h * C;
    float vs = 0.f, vd = 0.f;
#pragma unroll 8
    for (int c = 0; c < C; ++c) { float w = wr[c]; vs += w * ar[c]; vd += w * dr[c]; }
    lws[i] = vs; lwd[i] = vd;
  }
  __syncthreads();
  // main GEMM: each thread owns one output column for 16 rows
  float acc[16];
#pragma unroll
  for (int i = 0; i < 16; ++i) acc[i] = 0.f;
  for (int k = 0; k < 64; k += 4) {
    float w0 = W[(k + 0) * HC + tid];
    float w1 = W[(k + 1) * HC + tid];
    float w2 = W[(k + 2) * HC + tid];
    float w3 = W[(k + 3) * HC + tid];
#pragma unroll
    for (int i = 0; i < 16; ++i) {
      float4 hv = *(const float4*)&hs[i * 64 + k];
      acc[i] += hv.x * w0 + hv.y * w1 + hv.z * w2 + hv.w * w3;
    }
  }
#pragma unroll
  for (int i = 0; i < 16; ++i) {
    int n = n0 + i;
    if (n < p.N) p.xpb[(size_t)n * HC + tid] = f2bf(acc[i]);
  }
  // logits: 64 threads = (node i, head h) pairs; dot from LDS
  if (tid < 64) {
    int i = tid >> 2, h = tid & 3;
    int n = n0 + i;
    float vs = 0.f, vd = 0.f;
#pragma unroll 8
    for (int k = 0; k < 64; ++k) {
      float hv = hs[i * 64 + k];
      vs += hv * lws[k * 4 + h];
      vd += hv * lwd[k * 4 + h];
    }
    if (n < p.N) {
      p.als[n * H4 + h] = vs;
      p.ald[n * H4 + h] = vd;
    }
  }
}

// ==================== kernels ====================

// layer-0 GEMM (blocks [0,gemmB)) || edge-degree count (blocks >= gemmB)
__global__ __launch_bounds__(TB) void k_gemm0_count(Pr p, const float* __restrict__ W,
                                                    const float* __restrict__ a_s,
                                                    const float* __restrict__ a_d,
                                                    int gemmB) {
  __shared__ float hs[1024];
  __shared__ float lws[256];
  __shared__ float lwd[256];
  if ((int)blockIdx.x >= gemmB) {
    int stride = ((int)gridDim.x - gemmB) * TB;
    for (int i = ((int)blockIdx.x - gemmB) * TB + threadIdx.x; i < p.E; i += stride)
      atomicAdd(&p.cursor[p.edst[i]], 1);
    return;
  }
  gemm_tile<256, true>(p, p.x, W, a_s, a_d, hs, lws, lwd, blockIdx.x << 4);
}

template <int HC>
__global__ __launch_bounds__(HC) void k_gemm_al(Pr p, const float* __restrict__ hin,
                                                const float* __restrict__ W,
                                                const float* __restrict__ a_s,
                                                const float* __restrict__ a_d) {
  __shared__ float hs[1024];
  __shared__ float lws[256];
  __shared__ float lwd[256];
  gemm_tile<HC, false>(p, hin, W, a_s, a_d, hs, lws, lwd, blockIdx.x << 4);
}

// parallel region allocator: wave shfl-scan + one atomicAdd per wave
__global__ void k_alloc(Pr p) {
  int gid = blockIdx.x * blockDim.x + threadIdx.x;
  int lane = threadIdx.x & 63;
  int size = (gid < p.N) ? (p.cursor[gid] + 1) : 0;  // +1 self-loop
  int v = size;
#pragma unroll
  for (int off = 1; off < 64; off <<= 1) {
    int t = __shfl_up(v, off, 64);
    if (lane >= off) v += t;
  }
  int tot = __shfl(v, 63, 64);
  int b0 = 0;
  if (lane == 63) b0 = atomicAdd(p.counter, tot);
  b0 = __shfl(b0, 63, 64);
  if (gid < p.N) {
    int pos = b0 + v - size;
    p.rbeg[gid] = pos;
    p.rend[gid] = pos + size;
    p.col[pos] = gid;  // self-loop
    p.cursor[gid] = pos + 1;
  }
}

__global__ void k_scatter(Pr p) {
  int gid = blockIdx.x * blockDim.x + threadIdx.x;
  if (gid < p.E) {
    int pos = atomicAdd(&p.cursor[p.edst[gid]], 1);
    p.col[pos] = p.esrc[gid];
  }
}

// gather: 2 waves per node (split edge range, LDS combine), 4 edges in flight.
// POOL variant: bucketed mean-pool atomics + last-block ticket runs the heads.
template <int C, bool RELU, bool POOL>
__global__ __launch_bounds__(128) void k_gather(Pr p, float* __restrict__ hout,
                                                const float* __restrict__ bias,
                                                const float* __restrict__ g,
                                                const float* __restrict__ be,
                                                const float* __restrict__ m,
                                                const float* __restrict__ v) {
  constexpr int HC = H4 * C;
  constexpr int VPL = HC / 64;  // 4 (C=64) or 2 (C=32)
  __shared__ float accbuf[HC];
  __shared__ float sbuf[H4];
  int sub = threadIdx.x >> 6;
  int lane = threadIdx.x & 63;
  int n = blockIdx.x;
  int h = lane >> 4;
  float aldn = p.ald[n * H4 + h];
  int beg = p.rbeg[n], end = p.rend[n];
  int len = end - beg;
  int lenA = (len + 1) >> 1;
  int jb = sub ? (beg + lenA) : beg;
  int je = sub ? end : (beg + lenA);

  float s = 0.f;
  float acc[VPL];
#pragma unroll
  for (int i = 0; i < VPL; ++i) acc[i] = 0.f;

  int j = jb;
  for (; j + 3 < je; j += 4) {
    int s0 = p.col[j], s1 = p.col[j + 1], s2 = p.col[j + 2], s3 = p.col[j + 3];
    float a0 = p.als[s0 * H4 + h], a1 = p.als[s1 * H4 + h];
    float a2 = p.als[s2 * H4 + h], a3 = p.als[s3 * H4 + h];
    float e0 = a0 + aldn; e0 = (e0 > 0.f) ? e0 : 0.2f * e0; e0 = __expf(e0);
    float e1 = a1 + aldn; e1 = (e1 > 0.f) ? e1 : 0.2f * e1; e1 = __expf(e1);
    float e2 = a2 + aldn; e2 = (e2 > 0.f) ? e2 : 0.2f * e2; e2 = __expf(e2);
    float e3 = a3 + aldn; e3 = (e3 > 0.f) ? e3 : 0.2f * e3; e3 = __expf(e3);
    s += (e0 + e1) + (e2 + e3);
    if constexpr (VPL == 4) {
      uint2 u0 = *(const uint2*)(p.xpb + (size_t)s0 * HC + lane * 4);
      uint2 u1 = *(const uint2*)(p.xpb + (size_t)s1 * HC + lane * 4);
      uint2 u2 = *(const uint2*)(p.xpb + (size_t)s2 * HC + lane * 4);
      uint2 u3 = *(const uint2*)(p.xpb + (size_t)s3 * HC + lane * 4);
      acc[0] += e0 * bfh(u0.x) + e1 * bfh(u1.x) + e2 * bfh(u2.x) + e3 * bfh(u3.x);
      acc[1] += e0 * bfl(u0.x) + e1 * bfl(u1.x) + e2 * bfl(u2.x) + e3 * bfl(u3.x);
      acc[2] += e0 * bfh(u0.y) + e1 * bfh(u1.y) + e2 * bfh(u2.y) + e3 * bfh(u3.y);
      acc[3] += e0 * bfl(u0.y) + e1 * bfl(u1.y) + e2 * bfl(u2.y) + e3 * bfl(u3.y);
    } else {
      unsigned u0 = *(const unsigned*)(p.xpb + (size_t)s0 * HC + lane * 2);
      unsigned u1 = *(const unsigned*)(p.xpb + (size_t)s1 * HC + lane * 2);
      unsigned u2 = *(const unsigned*)(p.xpb + (size_t)s2 * HC + lane * 2);
      unsigned u3 = *(const unsigned*)(p.xpb + (size_t)s3 * HC + lane * 2);
      acc[0] += e0 * bfh(u0) + e1 * bfh(u1) + e2 * bfh(u2) + e3 * bfh(u3);
      acc[1] += e0 * bfl(u0) + e1 * bfl(u1) + e2 * bfl(u2) + e3 * bfl(u3);
    }
  }
  for (; j < je; ++j) {
    int s0 = p.col[j];
    float a0 = p.als[s0 * H4 + h];
    float e0 = a0 + aldn; e0 = (e0 > 0.f) ? e0 : 0.2f * e0; e0 = __expf(e0);
    s += e0;
    if constexpr (VPL == 4) {
      uint2 u0 = *(const uint2*)(p.xpb + (size_t)s0 * HC + lane * 4);
      acc[0] += e0 * bfh(u0.x);
      acc[1] += e0 * bfl(u0.x);
      acc[2] += e0 * bfh(u0.y);
      acc[3] += e0 * bfl(u0.y);
    } else {
      unsigned u0 = *(const unsigned*)(p.xpb + (size_t)s0 * HC + lane * 2);
      acc[0] += e0 * bfh(u0);
      acc[1] += e0 * bfl(u0);
    }
  }

  // combine wave1 -> wave0
  if (sub) {
    if ((lane & 15) == 0) sbuf[h] = s;
#pragma unroll
    for (int i = 0; i < VPL; ++i) accbuf[lane * VPL + i] = acc[i];
  }
  __syncthreads();
  if (sub == 0) {
    s += sbuf[h];
#pragma unroll
    for (int i = 0; i < VPL; ++i) acc[i] += accbuf[lane * VPL + i];

    float inv = 1.f / (s + 1e-16f);
#pragma unroll
    for (int i = 0; i < VPL; ++i) {
      acc[i] *= inv;
      acc[i] += __shfl_xor(acc[i], 16, 64);  // head sum (bits 4,5 = head)
      acc[i] += __shfl_xor(acc[i], 32, 64);
    }
    if (lane < 16) {
      int c0 = lane * VPL;
      float o[VPL];
#pragma unroll
      for (int i = 0; i < VPL; ++i) {
        int cc = c0 + i;
        float t = acc[i] * (1.f / H4) + bias[cc];
        t = (t - m[cc]) * rsqrtf(v[cc] + 1e-5f) * g[cc] + be[cc];
        if (RELU) t = fmaxf(t, 0.f);
        o[i] = t;
        if (POOL) atomicAdd(&p.gpart[(n & 255) * 32 + cc], t);
      }
      if constexpr (VPL == 4)
        *(float4*)&hout[(size_t)n * C + c0] = make_float4(o[0], o[1], o[2], o[3]);
      else
        *(float2*)&hout[(size_t)n * C + c0] = make_float2(o[0], o[1]);
    }
  }

  if constexpr (POOL) {
    __shared__ int lastFlag;
    __shared__ float red[128];
    __shared__ float z[32];
    __shared__ float hid[32];
    __threadfence();
    __syncthreads();
    int tid = threadIdx.x;
    if (tid == 0) lastFlag = (atomicAdd(p.ticket, 1) == (int)gridDim.x - 1) ? 1 : 0;
    __syncthreads();
    if (!lastFlag) return;
    // last block: fold 256x32 buckets -> graph_emb -> 2 MLP heads
    int c = tid & 31;
    float sa = 0.f;
    for (int b = tid >> 5; b < 256; b += 4)
      sa += atomicAdd(&p.gpart[b * 32 + c], 0.f);  // coherent read
    red[tid] = sa;
    __syncthreads();
    size_t base = (size_t)p.N * 32;
    if (tid < 32) {
      float t = red[tid] + red[32 + tid] + red[64 + tid] + red[96 + tid];
      t /= (float)p.N;
      z[tid] = t;
      p.out[base + tid] = t;  // graph_emb
    }
    __syncthreads();
    if (tid < 16) {
      float a = p.eb1[tid], b = p.mb1[tid];
      for (int k = 0; k < 32; ++k) {
        a += z[k] * p.eW1[k * 16 + tid];
        b += z[k] * p.mW1[k * 16 + tid];
      }
      hid[tid] = fmaxf(a, 0.f);
      hid[16 + tid] = fmaxf(b, 0.f);
    }
    __syncthreads();
    if (tid == 0) {
      float a = p.eb2[0];
      for (int k = 0; k < 16; ++k) a += hid[k] * p.eW2[k];
      p.out[base + 32] = 1.f / (1.f + __expf(-a));
    } else if (tid == 1) {
      float a = p.mb2[0];
      for (int k = 0; k < 16; ++k) a += hid[16 + k] * p.mW2[k];
      p.out[base + 33] = 1.f / (1.f + __expf(-a));
    }
  }
}

// ==================== launch ====================
extern "C" void kernel_launch(void* const* d_in, const int* in_sizes, int n_in,
                              void* d_out, int out_size, void* d_ws, size_t ws_size,
                              hipStream_t stream) {
  const int N = in_sizes[0] / 5;
  const int E = in_sizes[1] / 2;
  const int M = E + N;

  Pr p;
  p.x = (const float*)d_in[0];
  const int* ei = (const int*)d_in[1];
  p.esrc = ei;
  p.edst = ei + E;
  p.encW = (const float*)d_in[2];
  p.encb = (const float*)d_in[3];
  const float* Wl[3]; const float* asl[3]; const float* adl[3]; const float* bl[3];
  const float* gl[3]; const float* bel[3]; const float* ml[3]; const float* vl[3];
  for (int l = 0; l < 3; ++l) {
    const int o = 4 + 8 * l;
    Wl[l]  = (const float*)d_in[o + 0];
    asl[l] = (const float*)d_in[o + 1];
    adl[l] = (const float*)d_in[o + 2];
    bl[l]  = (const float*)d_in[o + 3];
    gl[l]  = (const float*)d_in[o + 4];
    bel[l] = (const float*)d_in[o + 5];
    ml[l]  = (const float*)d_in[o + 6];
    vl[l]  = (const float*)d_in[o + 7];
  }
  p.eW1 = (const float*)d_in[28]; p.eb1 = (const float*)d_in[29];
  p.eW2 = (const float*)d_in[30]; p.eb2 = (const float*)d_in[31];
  p.mW1 = (const float*)d_in[32]; p.mb1 = (const float*)d_in[33];
  p.mW2 = (const float*)d_in[34]; p.mb2 = (const float*)d_in[35];
  p.out = (float*)d_out;
  p.N = N; p.E = E;

  float* wf = (float*)d_ws;
  size_t off = 0;
  p.hA = wf + off; off += (size_t)N * 64;
  p.hB = wf + off; off += (size_t)N * 64;
  p.xpb = (unsigned short*)(wf + off); off += (size_t)N * 128;  // N*256 bf16
  p.als = wf + off; off += (size_t)N * 4;
  p.ald = wf + off; off += (size_t)N * 4;
  int* wi = (int*)(wf + off);
  p.col = wi;                        // M
  p.rbeg = wi + M;                   // N
  p.rend = p.rbeg + N;               // N
  p.cursor = p.rend + N;             // N   } cursor, counter, ticket, gpart
  p.counter = p.cursor + N;          // 1   } contiguous -> single memset
  p.ticket = p.counter + 1;          // 1
  p.gpart = (float*)(p.ticket + 1);  // 256*32

  const int gE = (E + TB - 1) / TB;
  const int gN = (N + TB - 1) / TB;
  const int gGE = (N + 15) / 16;
  const int CNT = 256;  // counting blocks appended to layer-0 GEMM grid

  hipMemsetAsync(p.cursor, 0, (size_t)(N + 2) * sizeof(int) + 256 * 32 * sizeof(float), stream);

  // layer-0 GEMM (encoder fused) || edge count — independent roles, one kernel
  k_gemm0_count<<<gGE + CNT, TB, 0, stream>>>(p, Wl[0], asl[0], adl[0], gGE);
  k_alloc<<<gN, TB, 0, stream>>>(p);
  k_scatter<<<gE, TB, 0, stream>>>(p);

  k_gather<64, true, false><<<N, 128, 0, stream>>>(p, p.hB, bl[0], gl[0], bel[0], ml[0], vl[0]);
  k_gemm_al<256><<<gGE, 256, 0, stream>>>(p, p.hB, Wl[1], asl[1], adl[1]);
  k_gather<64, true, false><<<N, 128, 0, stream>>>(p, p.hA, bl[1], gl[1], bel[1], ml[1], vl[1]);
  k_gemm_al<128><<<gGE, 128, 0, stream>>>(p, p.hA, Wl[2], asl[2], adl[2]);
  k_gather<32, false, true><<<N, 128, 0, stream>>>(p, p.out, bl[2], gl[2], bel[2], ml[2], vl[2]);
}

// Round 11
// 371.663 us; speedup vs baseline: 2.9871x; 2.9871x over previous
//
#include <hip/hip_runtime.h>
#include <math.h>

// EthicalGNN: encoder -> 3x(GAT + BN (+ReLU)) -> mean-pool -> 2 MLP heads.
// R11: R10 minus the last-block ticket (20000 same-address cross-XCD atomics
// + per-block device fences cost ~770 us — ticket only viable for tiny
// grids). Heads back to a separate 1-block kernel. Keeps: edge-count merged
// into layer-0 GEMM, in-LDS was/wad logit projection, 2-wave/node gather.
// 9 kernels + 1 memset.

#define H4 4
constexpr int TB = 256;

static __device__ __forceinline__ unsigned short f2bf(float f) {
  unsigned u = __float_as_uint(f);
  u += 0x7fffu + ((u >> 16) & 1u);  // round-to-nearest-even
  return (unsigned short)(u >> 16);
}
static __device__ __forceinline__ float bfh(unsigned u) { return __uint_as_float(u << 16); }
static __device__ __forceinline__ float bfl(unsigned u) { return __uint_as_float(u & 0xffff0000u); }

struct Pr {
  const float* x; const int* esrc; const int* edst;
  const float* encW; const float* encb;
  const float* eW1; const float* eb1; const float* eW2; const float* eb2;
  const float* mW1; const float* mb1; const float* mW2; const float* mb2;
  float* hA; float* hB; unsigned short* xpb; float* als; float* ald;
  float* gpart;
  int* col; int* rbeg; int* rend; int* cursor; int* counter;
  float* out; int N; int E;
};

// ==================== GEMM tile (device fn) ====================
// xp(bf16) = hin @ W ; als/ald via in-LDS was/wad = W@a (reassociated).
template <int HC, bool ENC>
__device__ void gemm_tile(const Pr& p, const float* __restrict__ hin,
                          const float* __restrict__ W,
                          const float* __restrict__ a_s, const float* __restrict__ a_d,
                          float* hs, float* lws, float* lwd, int n0) {
  constexpr int C = HC / H4;
  int tid = threadIdx.x;
  if (ENC) {
    for (int idx = tid; idx < 1024; idx += HC) {
      int i = idx >> 6, j = idx & 63;
      int n = n0 + i;
      float a = 0.f;
      if (n < p.N) {
        a = p.encb[j];
#pragma unroll
        for (int k = 0; k < 5; ++k) a += p.x[n * 5 + k] * p.encW[k * 64 + j];
      }
      hs[idx] = a;
    }
  } else {
    for (int idx = tid; idx < 1024; idx += HC) {
      int n = n0 + (idx >> 6);
      hs[idx] = (n < p.N) ? hin[(size_t)n0 * 64 + idx] : 0.f;
    }
  }
  // was/wad[k,h] = sum_c W[k, h*C+c] * a[h,c]  (per-block, into LDS)
  for (int i = tid; i < 256; i += HC) {
    int k = i >> 2, h = i & 3;
    const float* wr = W + k * HC + h * C;
    const float* ar = a_s + h * C;
    const float* dr = a_d + h * C;
    float vs = 0.f, vd = 0.f;
#pragma unroll 8
    for (int c = 0; c < C; ++c) { float w = wr[c]; vs += w * ar[c]; vd += w * dr[c]; }
    lws[i] = vs; lwd[i] = vd;
  }
  __syncthreads();
  float acc[16];
#pragma unroll
  for (int i = 0; i < 16; ++i) acc[i] = 0.f;
  for (int k = 0; k < 64; k += 4) {
    float w0 = W[(k + 0) * HC + tid];
    float w1 = W[(k + 1) * HC + tid];
    float w2 = W[(k + 2) * HC + tid];
    float w3 = W[(k + 3) * HC + tid];
#pragma unroll
    for (int i = 0; i < 16; ++i) {
      float4 hv = *(const float4*)&hs[i * 64 + k];
      acc[i] += hv.x * w0 + hv.y * w1 + hv.z * w2 + hv.w * w3;
    }
  }
#pragma unroll
  for (int i = 0; i < 16; ++i) {
    int n = n0 + i;
    if (n < p.N) p.xpb[(size_t)n * HC + tid] = f2bf(acc[i]);
  }
  if (tid < 64) {  // logits: (node i, head h) pairs, dot from LDS
    int i = tid >> 2, h = tid & 3;
    int n = n0 + i;
    float vs = 0.f, vd = 0.f;
#pragma unroll 8
    for (int k = 0; k < 64; ++k) {
      float hv = hs[i * 64 + k];
      vs += hv * lws[k * 4 + h];
      vd += hv * lwd[k * 4 + h];
    }
    if (n < p.N) {
      p.als[n * H4 + h] = vs;
      p.ald[n * H4 + h] = vd;
    }
  }
}

// ==================== kernels ====================

// layer-0 GEMM (blocks [0,gemmB)) || edge-degree count (blocks >= gemmB)
__global__ __launch_bounds__(TB) void k_gemm0_count(Pr p, const float* __restrict__ W,
                                                    const float* __restrict__ a_s,
                                                    const float* __restrict__ a_d,
                                                    int gemmB) {
  __shared__ float hs[1024];
  __shared__ float lws[256];
  __shared__ float lwd[256];
  if ((int)blockIdx.x >= gemmB) {
    int stride = ((int)gridDim.x - gemmB) * TB;
    for (int i = ((int)blockIdx.x - gemmB) * TB + threadIdx.x; i < p.E; i += stride)
      atomicAdd(&p.cursor[p.edst[i]], 1);
    return;
  }
  gemm_tile<256, true>(p, p.x, W, a_s, a_d, hs, lws, lwd, blockIdx.x << 4);
}

template <int HC>
__global__ __launch_bounds__(HC) void k_gemm_al(Pr p, const float* __restrict__ hin,
                                                const float* __restrict__ W,
                                                const float* __restrict__ a_s,
                                                const float* __restrict__ a_d) {
  __shared__ float hs[1024];
  __shared__ float lws[256];
  __shared__ float lwd[256];
  gemm_tile<HC, false>(p, hin, W, a_s, a_d, hs, lws, lwd, blockIdx.x << 4);
}

// parallel region allocator: wave shfl-scan + one atomicAdd per wave
__global__ void k_alloc(Pr p) {
  int gid = blockIdx.x * blockDim.x + threadIdx.x;
  int lane = threadIdx.x & 63;
  int size = (gid < p.N) ? (p.cursor[gid] + 1) : 0;  // +1 self-loop
  int v = size;
#pragma unroll
  for (int off = 1; off < 64; off <<= 1) {
    int t = __shfl_up(v, off, 64);
    if (lane >= off) v += t;
  }
  int tot = __shfl(v, 63, 64);
  int b0 = 0;
  if (lane == 63) b0 = atomicAdd(p.counter, tot);
  b0 = __shfl(b0, 63, 64);
  if (gid < p.N) {
    int pos = b0 + v - size;
    p.rbeg[gid] = pos;
    p.rend[gid] = pos + size;
    p.col[pos] = gid;  // self-loop
    p.cursor[gid] = pos + 1;
  }
}

__global__ void k_scatter(Pr p) {
  int gid = blockIdx.x * blockDim.x + threadIdx.x;
  if (gid < p.E) {
    int pos = atomicAdd(&p.cursor[p.edst[gid]], 1);
    p.col[pos] = p.esrc[gid];
  }
}

// gather: 2 waves per node (split edge range, LDS combine), 4 edges in flight.
// POOL: bucketed mean-pool atomics only (NO ticket — heads in k_heads2).
template <int C, bool RELU, bool POOL>
__global__ __launch_bounds__(128) void k_gather(Pr p, float* __restrict__ hout,
                                                const float* __restrict__ bias,
                                                const float* __restrict__ g,
                                                const float* __restrict__ be,
                                                const float* __restrict__ m,
                                                const float* __restrict__ v) {
  constexpr int HC = H4 * C;
  constexpr int VPL = HC / 64;  // 4 (C=64) or 2 (C=32)
  __shared__ float accbuf[HC];
  __shared__ float sbuf[H4];
  int sub = threadIdx.x >> 6;
  int lane = threadIdx.x & 63;
  int n = blockIdx.x;
  int h = lane >> 4;
  float aldn = p.ald[n * H4 + h];
  int beg = p.rbeg[n], end = p.rend[n];
  int len = end - beg;
  int lenA = (len + 1) >> 1;
  int jb = sub ? (beg + lenA) : beg;
  int je = sub ? end : (beg + lenA);

  float s = 0.f;
  float acc[VPL];
#pragma unroll
  for (int i = 0; i < VPL; ++i) acc[i] = 0.f;

  int j = jb;
  for (; j + 3 < je; j += 4) {
    int s0 = p.col[j], s1 = p.col[j + 1], s2 = p.col[j + 2], s3 = p.col[j + 3];
    float a0 = p.als[s0 * H4 + h], a1 = p.als[s1 * H4 + h];
    float a2 = p.als[s2 * H4 + h], a3 = p.als[s3 * H4 + h];
    float e0 = a0 + aldn; e0 = (e0 > 0.f) ? e0 : 0.2f * e0; e0 = __expf(e0);
    float e1 = a1 + aldn; e1 = (e1 > 0.f) ? e1 : 0.2f * e1; e1 = __expf(e1);
    float e2 = a2 + aldn; e2 = (e2 > 0.f) ? e2 : 0.2f * e2; e2 = __expf(e2);
    float e3 = a3 + aldn; e3 = (e3 > 0.f) ? e3 : 0.2f * e3; e3 = __expf(e3);
    s += (e0 + e1) + (e2 + e3);
    if constexpr (VPL == 4) {
      uint2 u0 = *(const uint2*)(p.xpb + (size_t)s0 * HC + lane * 4);
      uint2 u1 = *(const uint2*)(p.xpb + (size_t)s1 * HC + lane * 4);
      uint2 u2 = *(const uint2*)(p.xpb + (size_t)s2 * HC + lane * 4);
      uint2 u3 = *(const uint2*)(p.xpb + (size_t)s3 * HC + lane * 4);
      acc[0] += e0 * bfh(u0.x) + e1 * bfh(u1.x) + e2 * bfh(u2.x) + e3 * bfh(u3.x);
      acc[1] += e0 * bfl(u0.x) + e1 * bfl(u1.x) + e2 * bfl(u2.x) + e3 * bfl(u3.x);
      acc[2] += e0 * bfh(u0.y) + e1 * bfh(u1.y) + e2 * bfh(u2.y) + e3 * bfh(u3.y);
      acc[3] += e0 * bfl(u0.y) + e1 * bfl(u1.y) + e2 * bfl(u2.y) + e3 * bfl(u3.y);
    } else {
      unsigned u0 = *(const unsigned*)(p.xpb + (size_t)s0 * HC + lane * 2);
      unsigned u1 = *(const unsigned*)(p.xpb + (size_t)s1 * HC + lane * 2);
      unsigned u2 = *(const unsigned*)(p.xpb + (size_t)s2 * HC + lane * 2);
      unsigned u3 = *(const unsigned*)(p.xpb + (size_t)s3 * HC + lane * 2);
      acc[0] += e0 * bfh(u0) + e1 * bfh(u1) + e2 * bfh(u2) + e3 * bfh(u3);
      acc[1] += e0 * bfl(u0) + e1 * bfl(u1) + e2 * bfl(u2) + e3 * bfl(u3);
    }
  }
  for (; j < je; ++j) {
    int s0 = p.col[j];
    float a0 = p.als[s0 * H4 + h];
    float e0 = a0 + aldn; e0 = (e0 > 0.f) ? e0 : 0.2f * e0; e0 = __expf(e0);
    s += e0;
    if constexpr (VPL == 4) {
      uint2 u0 = *(const uint2*)(p.xpb + (size_t)s0 * HC + lane * 4);
      acc[0] += e0 * bfh(u0.x);
      acc[1] += e0 * bfl(u0.x);
      acc[2] += e0 * bfh(u0.y);
      acc[3] += e0 * bfl(u0.y);
    } else {
      unsigned u0 = *(const unsigned*)(p.xpb + (size_t)s0 * HC + lane * 2);
      acc[0] += e0 * bfh(u0);
      acc[1] += e0 * bfl(u0);
    }
  }

  // combine wave1 -> wave0
  if (sub) {
    if ((lane & 15) == 0) sbuf[h] = s;
#pragma unroll
    for (int i = 0; i < VPL; ++i) accbuf[lane * VPL + i] = acc[i];
  }
  __syncthreads();
  if (sub) return;
  s += sbuf[h];
#pragma unroll
  for (int i = 0; i < VPL; ++i) acc[i] += accbuf[lane * VPL + i];

  float inv = 1.f / (s + 1e-16f);
#pragma unroll
  for (int i = 0; i < VPL; ++i) {
    acc[i] *= inv;
    acc[i] += __shfl_xor(acc[i], 16, 64);  // head sum (bits 4,5 = head)
    acc[i] += __shfl_xor(acc[i], 32, 64);
  }

  if (lane < 16) {
    int c0 = lane * VPL;
    float o[VPL];
#pragma unroll
    for (int i = 0; i < VPL; ++i) {
      int cc = c0 + i;
      float t = acc[i] * (1.f / H4) + bias[cc];
      t = (t - m[cc]) * rsqrtf(v[cc] + 1e-5f) * g[cc] + be[cc];
      if (RELU) t = fmaxf(t, 0.f);
      o[i] = t;
      if (POOL) atomicAdd(&p.gpart[(n & 255) * 32 + cc], t);
    }
    if constexpr (VPL == 4)
      *(float4*)&hout[(size_t)n * C + c0] = make_float4(o[0], o[1], o[2], o[3]);
    else
      *(float2*)&hout[(size_t)n * C + c0] = make_float2(o[0], o[1]);
  }
}

// ---------------- graph_emb + 2 MLP heads (1 block) ----------------
__global__ void k_heads2(Pr p) {
  __shared__ float red[256];
  __shared__ float z[32];
  __shared__ float hid[32];  // [0:16) ethics, [16:32) manip
  int tid = threadIdx.x;
  int c = tid & 31;
  float s = 0.f;
  for (int b = tid >> 5; b < 256; b += 8) s += p.gpart[b * 32 + c];
  red[tid] = s;
  __syncthreads();
  size_t base = (size_t)p.N * 32;
  if (tid < 32) {
    float t = 0.f;
#pragma unroll
    for (int i = 0; i < 8; ++i) t += red[i * 32 + tid];
    t /= (float)p.N;
    z[tid] = t;
    p.out[base + tid] = t;  // graph_emb
  }
  __syncthreads();
  if (tid < 16) {
    float a = p.eb1[tid], b = p.mb1[tid];
    for (int k = 0; k < 32; ++k) {
      a += z[k] * p.eW1[k * 16 + tid];
      b += z[k] * p.mW1[k * 16 + tid];
    }
    hid[tid] = fmaxf(a, 0.f);
    hid[16 + tid] = fmaxf(b, 0.f);
  }
  __syncthreads();
  if (tid == 0) {
    float a = p.eb2[0];
    for (int k = 0; k < 16; ++k) a += hid[k] * p.eW2[k];
    p.out[base + 32] = 1.f / (1.f + __expf(-a));
  } else if (tid == 1) {
    float a = p.mb2[0];
    for (int k = 0; k < 16; ++k) a += hid[16 + k] * p.mW2[k];
    p.out[base + 33] = 1.f / (1.f + __expf(-a));
  }
}

// ==================== launch ====================
extern "C" void kernel_launch(void* const* d_in, const int* in_sizes, int n_in,
                              void* d_out, int out_size, void* d_ws, size_t ws_size,
                              hipStream_t stream) {
  const int N = in_sizes[0] / 5;
  const int E = in_sizes[1] / 2;
  const int M = E + N;

  Pr p;
  p.x = (const float*)d_in[0];
  const int* ei = (const int*)d_in[1];
  p.esrc = ei;
  p.edst = ei + E;
  p.encW = (const float*)d_in[2];
  p.encb = (const float*)d_in[3];
  const float* Wl[3]; const float* asl[3]; const float* adl[3]; const float* bl[3];
  const float* gl[3]; const float* bel[3]; const float* ml[3]; const float* vl[3];
  for (int l = 0; l < 3; ++l) {
    const int o = 4 + 8 * l;
    Wl[l]  = (const float*)d_in[o + 0];
    asl[l] = (const float*)d_in[o + 1];
    adl[l] = (const float*)d_in[o + 2];
    bl[l]  = (const float*)d_in[o + 3];
    gl[l]  = (const float*)d_in[o + 4];
    bel[l] = (const float*)d_in[o + 5];
    ml[l]  = (const float*)d_in[o + 6];
    vl[l]  = (const float*)d_in[o + 7];
  }
  p.eW1 = (const float*)d_in[28]; p.eb1 = (const float*)d_in[29];
  p.eW2 = (const float*)d_in[30]; p.eb2 = (const float*)d_in[31];
  p.mW1 = (const float*)d_in[32]; p.mb1 = (const float*)d_in[33];
  p.mW2 = (const float*)d_in[34]; p.mb2 = (const float*)d_in[35];
  p.out = (float*)d_out;
  p.N = N; p.E = E;

  float* wf = (float*)d_ws;
  size_t off = 0;
  p.hA = wf + off; off += (size_t)N * 64;
  p.hB = wf + off; off += (size_t)N * 64;
  p.xpb = (unsigned short*)(wf + off); off += (size_t)N * 128;  // N*256 bf16
  p.als = wf + off; off += (size_t)N * 4;
  p.ald = wf + off; off += (size_t)N * 4;
  int* wi = (int*)(wf + off);
  p.col = wi;                          // M
  p.rbeg = wi + M;                     // N
  p.rend = p.rbeg + N;                 // N
  p.cursor = p.rend + N;               // N   } cursor, counter, gpart
  p.counter = p.cursor + N;            // 1   } contiguous -> single memset
  p.gpart = (float*)(p.counter + 1);   // 256*32

  const int gE = (E + TB - 1) / TB;
  const int gN = (N + TB - 1) / TB;
  const int gGE = (N + 15) / 16;
  const int CNT = 256;  // counting blocks appended to layer-0 GEMM grid

  hipMemsetAsync(p.cursor, 0, (size_t)(N + 1) * sizeof(int) + 256 * 32 * sizeof(float), stream);

  // layer-0 GEMM (encoder fused) || edge count — independent roles, one kernel
  k_gemm0_count<<<gGE + CNT, TB, 0, stream>>>(p, Wl[0], asl[0], adl[0], gGE);
  k_alloc<<<gN, TB, 0, stream>>>(p);
  k_scatter<<<gE, TB, 0, stream>>>(p);

  k_gather<64, true, false><<<N, 128, 0, stream>>>(p, p.hB, bl[0], gl[0], bel[0], ml[0], vl[0]);
  k_gemm_al<256><<<gGE, 256, 0, stream>>>(p, p.hB, Wl[1], asl[1], adl[1]);
  k_gather<64, true, false><<<N, 128, 0, stream>>>(p, p.hA, bl[1], gl[1], bel[1], ml[1], vl[1]);
  k_gemm_al<128><<<gGE, 128, 0, stream>>>(p, p.hA, Wl[2], asl[2], adl[2]);
  k_gather<32, false, true><<<N, 128, 0, stream>>>(p, p.out, bl[2], gl[2], bel[2], ml[2], vl[2]);

  k_heads2<<<1, 256, 0, stream>>>(p);
}

// Round 12
// 335.736 us; speedup vs baseline: 3.3067x; 1.1070x over previous
//
#include <hip/hip_runtime.h>
#include <math.h>

// EthicalGNN: encoder -> 3x(GAT + BN (+ReLU)) -> mean-pool -> 2 MLP heads.
// R12: was/wad projection computed ONCE in k_prep (3 blocks) -> global
// pas/pad; GEMMs stage it into LDS coalesced (R11's per-block recompute cost
// ~37us of uncoalesced L2 reads in gemm0 alone). Keeps count||gemm0 merge,
// 2-wave/node gather, bucketed pool + 1-block heads. 10 kernels + 1 memset.

#define H4 4
constexpr int TB = 256;

static __device__ __forceinline__ unsigned short f2bf(float f) {
  unsigned u = __float_as_uint(f);
  u += 0x7fffu + ((u >> 16) & 1u);  // round-to-nearest-even
  return (unsigned short)(u >> 16);
}
static __device__ __forceinline__ float bfh(unsigned u) { return __uint_as_float(u << 16); }
static __device__ __forceinline__ float bfl(unsigned u) { return __uint_as_float(u & 0xffff0000u); }

struct Pr {
  const float* x; const int* esrc; const int* edst;
  const float* encW; const float* encb;
  const float* eW1; const float* eb1; const float* eW2; const float* eb2;
  const float* mW1; const float* mb1; const float* mW2; const float* mb2;
  float* hA; float* hB; unsigned short* xpb; float* als; float* ald;
  float* pas; float* pad; float* gpart;
  int* col; int* rbeg; int* rend; int* cursor; int* counter;
  float* out; int N; int E;
};

// ==================== GEMM tile (device fn) ====================
// xp(bf16) = hin @ W ; logits als/ald = hin @ was/wad (was/wad from global,
// staged into LDS coalesced).
template <int HC, bool ENC>
__device__ void gemm_tile(const Pr& p, const float* __restrict__ hin,
                          const float* __restrict__ W,
                          const float* __restrict__ was, const float* __restrict__ wad,
                          float* hs, float* lws, float* lwd, int n0) {
  int tid = threadIdx.x;
  if (ENC) {
    for (int idx = tid; idx < 1024; idx += HC) {
      int i = idx >> 6, j = idx & 63;
      int n = n0 + i;
      float a = 0.f;
      if (n < p.N) {
        a = p.encb[j];
#pragma unroll
        for (int k = 0; k < 5; ++k) a += p.x[n * 5 + k] * p.encW[k * 64 + j];
      }
      hs[idx] = a;
    }
  } else {
    for (int idx = tid; idx < 1024; idx += HC) {
      int n = n0 + (idx >> 6);
      hs[idx] = (n < p.N) ? hin[(size_t)n0 * 64 + idx] : 0.f;
    }
  }
  // stage precomputed was/wad (256 floats each) into LDS, coalesced
  for (int i = tid; i < 256; i += HC) {
    lws[i] = was[i];
    lwd[i] = wad[i];
  }
  __syncthreads();
  float acc[16];
#pragma unroll
  for (int i = 0; i < 16; ++i) acc[i] = 0.f;
  for (int k = 0; k < 64; k += 4) {
    float w0 = W[(k + 0) * HC + tid];
    float w1 = W[(k + 1) * HC + tid];
    float w2 = W[(k + 2) * HC + tid];
    float w3 = W[(k + 3) * HC + tid];
#pragma unroll
    for (int i = 0; i < 16; ++i) {
      float4 hv = *(const float4*)&hs[i * 64 + k];
      acc[i] += hv.x * w0 + hv.y * w1 + hv.z * w2 + hv.w * w3;
    }
  }
#pragma unroll
  for (int i = 0; i < 16; ++i) {
    int n = n0 + i;
    if (n < p.N) p.xpb[(size_t)n * HC + tid] = f2bf(acc[i]);
  }
  if (tid < 64) {  // logits: (node i, head h) pairs, dot from LDS
    int i = tid >> 2, h = tid & 3;
    int n = n0 + i;
    float vs = 0.f, vd = 0.f;
#pragma unroll 8
    for (int k = 0; k < 64; ++k) {
      float hv = hs[i * 64 + k];
      vs += hv * lws[k * 4 + h];
      vd += hv * lwd[k * 4 + h];
    }
    if (n < p.N) {
      p.als[n * H4 + h] = vs;
      p.ald[n * H4 + h] = vd;
    }
  }
}

// ==================== kernels ====================

// was/wad[k,h] = sum_c W[k, h*C+c] * a[h,c] — computed ONCE, 3 blocks (layer each)
__global__ void k_prep(Pr p,
                       const float* __restrict__ W0, const float* __restrict__ as0, const float* __restrict__ ad0,
                       const float* __restrict__ W1, const float* __restrict__ as1, const float* __restrict__ ad1,
                       const float* __restrict__ W2, const float* __restrict__ as2, const float* __restrict__ ad2) {
  int l = blockIdx.x;
  const float* W  = (l == 0) ? W0 : (l == 1) ? W1 : W2;
  const float* ap = (l == 0) ? as0 : (l == 1) ? as1 : as2;
  const float* dp = (l == 0) ? ad0 : (l == 1) ? ad1 : ad2;
  int HC = (l == 2) ? 128 : 256;
  int C  = HC / H4;
  int tid = threadIdx.x;  // k*4 + h
  int k = tid >> 2, h = tid & 3;
  float vs = 0.f, vd = 0.f;
  for (int c = 0; c < C; ++c) {
    float w = W[k * HC + h * C + c];
    vs += w * ap[h * C + c];
    vd += w * dp[h * C + c];
  }
  p.pas[l * 256 + tid] = vs;
  p.pad[l * 256 + tid] = vd;
}

// layer-0 GEMM (blocks [0,gemmB)) || edge-degree count (blocks >= gemmB)
__global__ __launch_bounds__(TB) void k_gemm0_count(Pr p, const float* __restrict__ W,
                                                    int gemmB) {
  __shared__ float hs[1024];
  __shared__ float lws[256];
  __shared__ float lwd[256];
  if ((int)blockIdx.x >= gemmB) {
    int stride = ((int)gridDim.x - gemmB) * TB;
    for (int i = ((int)blockIdx.x - gemmB) * TB + threadIdx.x; i < p.E; i += stride)
      atomicAdd(&p.cursor[p.edst[i]], 1);
    return;
  }
  gemm_tile<256, true>(p, p.x, W, p.pas, p.pad, hs, lws, lwd, blockIdx.x << 4);
}

template <int HC>
__global__ __launch_bounds__(HC) void k_gemm_al(Pr p, const float* __restrict__ hin,
                                                const float* __restrict__ W,
                                                const float* __restrict__ was,
                                                const float* __restrict__ wad) {
  __shared__ float hs[1024];
  __shared__ float lws[256];
  __shared__ float lwd[256];
  gemm_tile<HC, false>(p, hin, W, was, wad, hs, lws, lwd, blockIdx.x << 4);
}

// parallel region allocator: wave shfl-scan + one atomicAdd per wave
__global__ void k_alloc(Pr p) {
  int gid = blockIdx.x * blockDim.x + threadIdx.x;
  int lane = threadIdx.x & 63;
  int size = (gid < p.N) ? (p.cursor[gid] + 1) : 0;  // +1 self-loop
  int v = size;
#pragma unroll
  for (int off = 1; off < 64; off <<= 1) {
    int t = __shfl_up(v, off, 64);
    if (lane >= off) v += t;
  }
  int tot = __shfl(v, 63, 64);
  int b0 = 0;
  if (lane == 63) b0 = atomicAdd(p.counter, tot);
  b0 = __shfl(b0, 63, 64);
  if (gid < p.N) {
    int pos = b0 + v - size;
    p.rbeg[gid] = pos;
    p.rend[gid] = pos + size;
    p.col[pos] = gid;  // self-loop
    p.cursor[gid] = pos + 1;
  }
}

__global__ void k_scatter(Pr p) {
  int gid = blockIdx.x * blockDim.x + threadIdx.x;
  if (gid < p.E) {
    int pos = atomicAdd(&p.cursor[p.edst[gid]], 1);
    p.col[pos] = p.esrc[gid];
  }
}

// gather: 2 waves per node (split edge range, LDS combine), 4 edges in flight.
// POOL: bucketed mean-pool atomics only (heads in k_heads2).
template <int C, bool RELU, bool POOL>
__global__ __launch_bounds__(128) void k_gather(Pr p, float* __restrict__ hout,
                                                const float* __restrict__ bias,
                                                const float* __restrict__ g,
                                                const float* __restrict__ be,
                                                const float* __restrict__ m,
                                                const float* __restrict__ v) {
  constexpr int HC = H4 * C;
  constexpr int VPL = HC / 64;  // 4 (C=64) or 2 (C=32)
  __shared__ float accbuf[HC];
  __shared__ float sbuf[H4];
  int sub = threadIdx.x >> 6;
  int lane = threadIdx.x & 63;
  int n = blockIdx.x;
  int h = lane >> 4;
  float aldn = p.ald[n * H4 + h];
  int beg = p.rbeg[n], end = p.rend[n];
  int len = end - beg;
  int lenA = (len + 1) >> 1;
  int jb = sub ? (beg + lenA) : beg;
  int je = sub ? end : (beg + lenA);

  float s = 0.f;
  float acc[VPL];
#pragma unroll
  for (int i = 0; i < VPL; ++i) acc[i] = 0.f;

  int j = jb;
  for (; j + 3 < je; j += 4) {
    int s0 = p.col[j], s1 = p.col[j + 1], s2 = p.col[j + 2], s3 = p.col[j + 3];
    float a0 = p.als[s0 * H4 + h], a1 = p.als[s1 * H4 + h];
    float a2 = p.als[s2 * H4 + h], a3 = p.als[s3 * H4 + h];
    float e0 = a0 + aldn; e0 = (e0 > 0.f) ? e0 : 0.2f * e0; e0 = __expf(e0);
    float e1 = a1 + aldn; e1 = (e1 > 0.f) ? e1 : 0.2f * e1; e1 = __expf(e1);
    float e2 = a2 + aldn; e2 = (e2 > 0.f) ? e2 : 0.2f * e2; e2 = __expf(e2);
    float e3 = a3 + aldn; e3 = (e3 > 0.f) ? e3 : 0.2f * e3; e3 = __expf(e3);
    s += (e0 + e1) + (e2 + e3);
    if constexpr (VPL == 4) {
      uint2 u0 = *(const uint2*)(p.xpb + (size_t)s0 * HC + lane * 4);
      uint2 u1 = *(const uint2*)(p.xpb + (size_t)s1 * HC + lane * 4);
      uint2 u2 = *(const uint2*)(p.xpb + (size_t)s2 * HC + lane * 4);
      uint2 u3 = *(const uint2*)(p.xpb + (size_t)s3 * HC + lane * 4);
      acc[0] += e0 * bfh(u0.x) + e1 * bfh(u1.x) + e2 * bfh(u2.x) + e3 * bfh(u3.x);
      acc[1] += e0 * bfl(u0.x) + e1 * bfl(u1.x) + e2 * bfl(u2.x) + e3 * bfl(u3.x);
      acc[2] += e0 * bfh(u0.y) + e1 * bfh(u1.y) + e2 * bfh(u2.y) + e3 * bfh(u3.y);
      acc[3] += e0 * bfl(u0.y) + e1 * bfl(u1.y) + e2 * bfl(u2.y) + e3 * bfl(u3.y);
    } else {
      unsigned u0 = *(const unsigned*)(p.xpb + (size_t)s0 * HC + lane * 2);
      unsigned u1 = *(const unsigned*)(p.xpb + (size_t)s1 * HC + lane * 2);
      unsigned u2 = *(const unsigned*)(p.xpb + (size_t)s2 * HC + lane * 2);
      unsigned u3 = *(const unsigned*)(p.xpb + (size_t)s3 * HC + lane * 2);
      acc[0] += e0 * bfh(u0) + e1 * bfh(u1) + e2 * bfh(u2) + e3 * bfh(u3);
      acc[1] += e0 * bfl(u0) + e1 * bfl(u1) + e2 * bfl(u2) + e3 * bfl(u3);
    }
  }
  for (; j < je; ++j) {
    int s0 = p.col[j];
    float a0 = p.als[s0 * H4 + h];
    float e0 = a0 + aldn; e0 = (e0 > 0.f) ? e0 : 0.2f * e0; e0 = __expf(e0);
    s += e0;
    if constexpr (VPL == 4) {
      uint2 u0 = *(const uint2*)(p.xpb + (size_t)s0 * HC + lane * 4);
      acc[0] += e0 * bfh(u0.x);
      acc[1] += e0 * bfl(u0.x);
      acc[2] += e0 * bfh(u0.y);
      acc[3] += e0 * bfl(u0.y);
    } else {
      unsigned u0 = *(const unsigned*)(p.xpb + (size_t)s0 * HC + lane * 2);
      acc[0] += e0 * bfh(u0);
      acc[1] += e0 * bfl(u0);
    }
  }

  // combine wave1 -> wave0
  if (sub) {
    if ((lane & 15) == 0) sbuf[h] = s;
#pragma unroll
    for (int i = 0; i < VPL; ++i) accbuf[lane * VPL + i] = acc[i];
  }
  __syncthreads();
  if (sub) return;
  s += sbuf[h];
#pragma unroll
  for (int i = 0; i < VPL; ++i) acc[i] += accbuf[lane * VPL + i];

  float inv = 1.f / (s + 1e-16f);
#pragma unroll
  for (int i = 0; i < VPL; ++i) {
    acc[i] *= inv;
    acc[i] += __shfl_xor(acc[i], 16, 64);  // head sum (bits 4,5 = head)
    acc[i] += __shfl_xor(acc[i], 32, 64);
  }

  if (lane < 16) {
    int c0 = lane * VPL;
    float o[VPL];
#pragma unroll
    for (int i = 0; i < VPL; ++i) {
      int cc = c0 + i;
      float t = acc[i] * (1.f / H4) + bias[cc];
      t = (t - m[cc]) * rsqrtf(v[cc] + 1e-5f) * g[cc] + be[cc];
      if (RELU) t = fmaxf(t, 0.f);
      o[i] = t;
      if (POOL) atomicAdd(&p.gpart[(n & 255) * 32 + cc], t);
    }
    if constexpr (VPL == 4)
      *(float4*)&hout[(size_t)n * C + c0] = make_float4(o[0], o[1], o[2], o[3]);
    else
      *(float2*)&hout[(size_t)n * C + c0] = make_float2(o[0], o[1]);
  }
}

// ---------------- graph_emb + 2 MLP heads (1 block) ----------------
__global__ void k_heads2(Pr p) {
  __shared__ float red[256];
  __shared__ float z[32];
  __shared__ float hid[32];  // [0:16) ethics, [16:32) manip
  int tid = threadIdx.x;
  int c = tid & 31;
  float s = 0.f;
  for (int b = tid >> 5; b < 256; b += 8) s += p.gpart[b * 32 + c];
  red[tid] = s;
  __syncthreads();
  size_t base = (size_t)p.N * 32;
  if (tid < 32) {
    float t = 0.f;
#pragma unroll
    for (int i = 0; i < 8; ++i) t += red[i * 32 + tid];
    t /= (float)p.N;
    z[tid] = t;
    p.out[base + tid] = t;  // graph_emb
  }
  __syncthreads();
  if (tid < 16) {
    float a = p.eb1[tid], b = p.mb1[tid];
    for (int k = 0; k < 32; ++k) {
      a += z[k] * p.eW1[k * 16 + tid];
      b += z[k] * p.mW1[k * 16 + tid];
    }
    hid[tid] = fmaxf(a, 0.f);
    hid[16 + tid] = fmaxf(b, 0.f);
  }
  __syncthreads();
  if (tid == 0) {
    float a = p.eb2[0];
    for (int k = 0; k < 16; ++k) a += hid[k] * p.eW2[k];
    p.out[base + 32] = 1.f / (1.f + __expf(-a));
  } else if (tid == 1) {
    float a = p.mb2[0];
    for (int k = 0; k < 16; ++k) a += hid[16 + k] * p.mW2[k];
    p.out[base + 33] = 1.f / (1.f + __expf(-a));
  }
}

// ==================== launch ====================
extern "C" void kernel_launch(void* const* d_in, const int* in_sizes, int n_in,
                              void* d_out, int out_size, void* d_ws, size_t ws_size,
                              hipStream_t stream) {
  const int N = in_sizes[0] / 5;
  const int E = in_sizes[1] / 2;
  const int M = E + N;

  Pr p;
  p.x = (const float*)d_in[0];
  const int* ei = (const int*)d_in[1];
  p.esrc = ei;
  p.edst = ei + E;
  p.encW = (const float*)d_in[2];
  p.encb = (const float*)d_in[3];
  const float* Wl[3]; const float* asl[3]; const float* adl[3]; const float* bl[3];
  const float* gl[3]; const float* bel[3]; const float* ml[3]; const float* vl[3];
  for (int l = 0; l < 3; ++l) {
    const int o = 4 + 8 * l;
    Wl[l]  = (const float*)d_in[o + 0];
    asl[l] = (const float*)d_in[o + 1];
    adl[l] = (const float*)d_in[o + 2];
    bl[l]  = (const float*)d_in[o + 3];
    gl[l]  = (const float*)d_in[o + 4];
    bel[l] = (const float*)d_in[o + 5];
    ml[l]  = (const float*)d_in[o + 6];
    vl[l]  = (const float*)d_in[o + 7];
  }
  p.eW1 = (const float*)d_in[28]; p.eb1 = (const float*)d_in[29];
  p.eW2 = (const float*)d_in[30]; p.eb2 = (const float*)d_in[31];
  p.mW1 = (const float*)d_in[32]; p.mb1 = (const float*)d_in[33];
  p.mW2 = (const float*)d_in[34]; p.mb2 = (const float*)d_in[35];
  p.out = (float*)d_out;
  p.N = N; p.E = E;

  float* wf = (float*)d_ws;
  size_t off = 0;
  p.hA = wf + off; off += (size_t)N * 64;
  p.hB = wf + off; off += (size_t)N * 64;
  p.xpb = (unsigned short*)(wf + off); off += (size_t)N * 128;  // N*256 bf16
  p.als = wf + off; off += (size_t)N * 4;
  p.ald = wf + off; off += (size_t)N * 4;
  p.pas = wf + off; off += 3 * 256;
  p.pad = wf + off; off += 3 * 256;
  int* wi = (int*)(wf + off);
  p.col = wi;                          // M
  p.rbeg = wi + M;                     // N
  p.rend = p.rbeg + N;                 // N
  p.cursor = p.rend + N;               // N   } cursor, counter, gpart
  p.counter = p.cursor + N;            // 1   } contiguous -> single memset
  p.gpart = (float*)(p.counter + 1);   // 256*32

  const int gE = (E + TB - 1) / TB;
  const int gN = (N + TB - 1) / TB;
  const int gGE = (N + 15) / 16;
  const int CNT = 256;  // counting blocks appended to layer-0 GEMM grid

  hipMemsetAsync(p.cursor, 0, (size_t)(N + 1) * sizeof(int) + 256 * 32 * sizeof(float), stream);

  // was/wad projections (once) — 3 tiny blocks
  k_prep<<<3, 256, 0, stream>>>(p, Wl[0], asl[0], adl[0], Wl[1], asl[1], adl[1],
                                Wl[2], asl[2], adl[2]);

  // layer-0 GEMM (encoder fused) || edge count — independent roles, one kernel
  k_gemm0_count<<<gGE + CNT, TB, 0, stream>>>(p, Wl[0], gGE);
  k_alloc<<<gN, TB, 0, stream>>>(p);
  k_scatter<<<gE, TB, 0, stream>>>(p);

  k_gather<64, true, false><<<N, 128, 0, stream>>>(p, p.hB, bl[0], gl[0], bel[0], ml[0], vl[0]);
  k_gemm_al<256><<<gGE, 256, 0, stream>>>(p, p.hB, Wl[1], p.pas + 256, p.pad + 256);
  k_gather<64, true, false><<<N, 128, 0, stream>>>(p, p.hA, bl[1], gl[1], bel[1], ml[1], vl[1]);
  k_gemm_al<128><<<gGE, 128, 0, stream>>>(p, p.hA, Wl[2], p.pas + 512, p.pad + 512);
  k_gather<32, false, true><<<N, 128, 0, stream>>>(p, p.out, bl[2], gl[2], bel[2], ml[2], vl[2]);

  k_heads2<<<1, 256, 0, stream>>>(p);
}